// Round 17
// baseline (90.345 us; speedup 1.0000x reference)
//
#include <hip/hip_runtime.h>
#include <stdint.h>

// BinarizeLinear: out[i][j] = sum_k sign(x[i][k]) * sign(W[j][k]) + bias[j]
// R17 = R13 (champion, 82.6 µs) re-tiled for TLP depth: 128x128 block,
// 256 threads (4 waves of 64x64), 32 KB LDS -> 3 blocks/CU co-resident
// (vs R13's 2). Schedule, swizzle, vmcnt ledger = R11/R13 hardware-verified
// pattern, pure parameter translation:
//   reads -> lgkm(0) -> BAR -> STAGE(cur,t+2) -> MFMA -> vmcnt(4) -> BAR
// (4 gl_lds/wave/iter: 2 A + 2 B; vmcnt(4) retires tile t+1's 4 stages).
// No min-waves launch bound: compiler allocates ~130 regs -> 3 waves/SIMD,
// no spill (R6 lesson). 2048 blocks (%8==0, XCD-bijective) -> ~2.7 rounds,
// finer C-store interleave + smaller exposed final drain.
// R14/R15/R16 (bigger wave tile, 32x32 shape, 8-phase) all regressed: ILP-side
// changes lose; this is the TLP-side lever.
// Exact: fp4 e2m1 +-1 (0x2/0xA), scale E8M0 0x7F=1.0, f32 accum, sums <= 2048.

#define Mdim 16384
#define Ndim 2048
#define Kdim 2048
#define NT 16  // K-tiles of 128 fp4 (64 B rows)

using i32x4 = __attribute__((ext_vector_type(4))) int;
using i32x8 = __attribute__((ext_vector_type(8))) int;
using f32x4 = __attribute__((ext_vector_type(4))) float;

// Binarize f32 -> packed fp4 (+1=0x2, -1=0xA), 16 f32 -> 8 bytes per thread.
__global__ __launch_bounds__(256) void binarize_fp4(const float* __restrict__ x,
                                                    const float* __restrict__ w,
                                                    uint8_t* __restrict__ out,
                                                    int nx16, int ntot16) {
  int i = blockIdx.x * 256 + threadIdx.x;
  if (i >= ntot16) return;
  const float4* p = (i < nx16) ? ((const float4*)x + (size_t)i * 4)
                               : ((const float4*)w + (size_t)(i - nx16) * 4);
  float4 f0 = p[0], f1 = p[1], f2 = p[2], f3 = p[3];
  float s[16] = {f0.x, f0.y, f0.z, f0.w, f1.x, f1.y, f1.z, f1.w,
                 f2.x, f2.y, f2.z, f2.w, f3.x, f3.y, f3.z, f3.w};
  union { uint8_t b[8]; uint2 v; } u;
#pragma unroll
  for (int j = 0; j < 8; ++j) {
    const unsigned lo = s[2 * j] > 0.0f ? 0x2u : 0xAu;
    const unsigned hi = s[2 * j + 1] > 0.0f ? 0x2u : 0xAu;
    u.b[j] = (uint8_t)(lo | (hi << 4));
  }
  ((uint2*)out)[i] = u.v;  // xb4 then wb4, contiguous
}

__device__ __forceinline__ void gl_lds16(const void* gsrc, void* ldst) {
  __builtin_amdgcn_global_load_lds(
      (const __attribute__((address_space(1))) void*)gsrc,
      (__attribute__((address_space(3))) void*)ldst, 16, 0, 0);
}

// fp4 f8f6f4 reads only regs [0:3] of the 8-reg operand: high half undef.
__device__ __forceinline__ i32x8 ext8(i32x4 v) {
  return __builtin_shufflevector(v, v, 0, 1, 2, 3, -1, -1, -1, -1);
}

__global__ __launch_bounds__(256) void bin_gemm_fp4_t3(const uint8_t* __restrict__ A4,
                                                       const uint8_t* __restrict__ W4,
                                                       const float* __restrict__ bias,
                                                       float* __restrict__ C) {
  // Row = 64 B = 128 fp4 of one K-tile. A: [2][128 rows], B: [2][128 rows]. 32 KB.
  __shared__ __align__(16) uint8_t As[2][128 * 64];
  __shared__ __align__(16) uint8_t Bs[2][128 * 64];

  const int tid = threadIdx.x;
  const int lane = tid & 63;
  const int wid = tid >> 6;  // 0..3
  const int wm = wid >> 1;   // 0..1 (M half: 64 rows)
  const int wn = wid & 1;    // 0..1 (N half: 64 cols)

  // XCD swizzle: 2048 blocks, %8==0 -> bijective; consecutive swz per XCD
  // sweep N-tiles fastest -> A-panel sharers co-XCD (L2 reuse).
  const int bid = blockIdx.x;
  const int swz = (bid & 7) * 256 + (bid >> 3);
  const long brow = (long)(swz >> 4) * 128;  // 128 M-tiles
  const long bcol = (long)(swz & 15) * 128;  // 16 N-tiles

  const long rowBytes = Kdim / 2;  // 1024 B per logical row

  // ---- staging: linear LDS dest; swizzle on global SOURCE slot.
  // 16 rows per gl_lds (4 lanes x 16 B per 64 B row); f(row)=(row>>1)&3 with
  // row = 16k + (lane>>2) -> f = (lane>>3)&3 (k-independent).
  const int sgcol = ((lane & 3) ^ ((lane >> 3) & 3)) * 16;
  const int srAB = wid * 32 + (lane >> 2);  // 2 gl_lds per operand (+0, +16)

  // ---- fragment ds_read offsets (swizzled: slot ^ ((row>>1)&3)) ----
  int offA[4], offB[4];
#pragma unroll
  for (int fr = 0; fr < 4; ++fr) {
    const int ra = wm * 64 + fr * 16 + (lane & 15);
    const int s = lane >> 4;
    offA[fr] = ra * 64 + ((s ^ ((ra >> 1) & 3)) * 16);
  }
#pragma unroll
  for (int fc = 0; fc < 4; ++fc) {
    const int rb = wn * 64 + fc * 16 + (lane & 15);
    const int s = lane >> 4;
    offB[fc] = rb * 64 + ((s ^ ((rb >> 1) & 3)) * 16);
  }

  f32x4 acc[4][4] = {};  // 64 regs
  i32x4 a[4], b[4];      // 16 + 16 regs

#define BAR() asm volatile("s_barrier" ::: "memory")
#define STAGE(BUF, KT)                                                                \
  do {                                                                                \
    const uint8_t* sa_ = A4 + (brow + srAB) * rowBytes + ((long)(KT) << 6) + sgcol;   \
    gl_lds16(sa_, &As[BUF][wid * 2048]);                                              \
    gl_lds16(sa_ + 16 * rowBytes, &As[BUF][wid * 2048 + 1024]);                       \
    const uint8_t* sb_ = W4 + (bcol + srAB) * rowBytes + ((long)(KT) << 6) + sgcol;   \
    gl_lds16(sb_, &Bs[BUF][wid * 2048]);                                              \
    gl_lds16(sb_ + 16 * rowBytes, &Bs[BUF][wid * 2048 + 1024]);                       \
  } while (0)

  // ---- prologue: stage tiles 0,1 (4 gl_lds/wave each); tile0 resident.
  STAGE(0, 0);
  STAGE(1, 1);
  asm volatile("s_waitcnt vmcnt(4)" ::: "memory");
  BAR();

#pragma unroll 1
  for (int t = 0; t < NT; ++t) {
    const int cur = t & 1;

    // reads of buf cur (8 x ds_read_b128), drained before the barrier
#pragma unroll
    for (int fr = 0; fr < 4; ++fr) a[fr] = *(const i32x4*)&As[cur][offA[fr]];
#pragma unroll
    for (int fc = 0; fc < 4; ++fc) b[fc] = *(const i32x4*)&Bs[cur][offB[fc]];
    asm volatile("s_waitcnt lgkmcnt(0)" ::: "memory");
    BAR();  // all waves done reading buf cur

    // overwrite cur with tile t+2 (post-barrier: safe)
    if (t + 2 < NT) STAGE(cur, t + 2);

    __builtin_amdgcn_s_setprio(1);
#pragma unroll
    for (int fr = 0; fr < 4; ++fr) {
      const i32x8 a8 = ext8(a[fr]);
#pragma unroll
      for (int fc = 0; fc < 4; ++fc) {
        // cbsz=4 (A=fp4), blgp=4 (B=fp4); scales E8M0 0x7F = 1.0 (exact).
        acc[fr][fc] = __builtin_amdgcn_mfma_scale_f32_16x16x128_f8f6f4(
            a8, ext8(b[fc]), acc[fr][fc], 4, 4, 0, 0x7F7F7F7F, 0, 0x7F7F7F7F);
      }
    }
    __builtin_amdgcn_s_setprio(0);

    // retire tile t+1's 4 stages (4 newest = tile t+2's, just issued)
    if (t < NT - 2) {
      asm volatile("s_waitcnt vmcnt(4)" ::: "memory");
    } else {
      asm volatile("s_waitcnt vmcnt(0)" ::: "memory");
    }
    BAR();
  }

  // ---- epilogue: C/D layout col=lane&15, row=(lane>>4)*4+reg ----
#pragma unroll
  for (int fc = 0; fc < 4; ++fc) {
    const long col = bcol + wn * 64 + fc * 16 + (lane & 15);
    const float bj = bias[col];
#pragma unroll
    for (int fr = 0; fr < 4; ++fr) {
      const long row0 = brow + wm * 64 + fr * 16 + (lane >> 4) * 4;
#pragma unroll
      for (int r = 0; r < 4; ++r) {
        C[(row0 + r) * (long)Ndim + col] = acc[fr][fc][r] + bj;
      }
    }
  }
#undef BAR
#undef STAGE
}

extern "C" void kernel_launch(void* const* d_in, const int* in_sizes, int n_in,
                              void* d_out, int out_size, void* d_ws, size_t ws_size,
                              hipStream_t stream) {
  const float* x = (const float*)d_in[0];
  const float* w = (const float*)d_in[1];
  const float* bias = (const float*)d_in[2];
  float* out = (float*)d_out;

  uint8_t* xb4 = (uint8_t*)d_ws;                 // 16.8 MB (fp4-packed)
  uint8_t* wb4 = xb4 + (size_t)Mdim * Kdim / 2;  // + 2.1 MB (ws >= 18.9 MB)

  const int nx16 = Mdim * Kdim / 16;  // 16-f32 units
  const int nw16 = Ndim * Kdim / 16;
  const int ntot16 = nx16 + nw16;
  binarize_fp4<<<(ntot16 + 255) / 256, 256, 0, stream>>>(x, w, xb4, nx16, ntot16);

  dim3 grid((Mdim / 128) * (Ndim / 128));  // 2048 blocks, %8==0
  bin_gemm_fp4_t3<<<grid, 256, 0, stream>>>(xb4, wb4, bias, out);
}

// Round 18
// 85.369 us; speedup vs baseline: 1.0583x; 1.0583x over previous
//
#include <hip/hip_runtime.h>
#include <stdint.h>

// BinarizeLinear: out[i][j] = sum_k sign(x[i][k]) * sign(W[j][k]) + bias[j]
// R18 = R13 (champion 82.6 µs: MX-FP4 2-phase, 128x256 tile, 8 waves 64x64,
// BK=128 fp4) with the mid-iteration barrier removed via TRIPLE BUFFER:
// stage tile t+2 into buf (t+2)%3 at the TOP of iter t (that buffer's last
// reads were iter t-1, lgkm-drained before t-1's MFMA and separated by the
// end-of-t-1 barrier) -> 1 barrier/iter instead of 2, and each gl_lds gets a
// full extra MFMA phase of flight time.
// Ledger: end of iter t, own outstanding = t+1 stages (3) + t+2 stages (3);
// vmcnt(3) retires t+1, BAR publishes across waves -> iter t+1 reads safe.
// Tail t >= NT-2: vmcnt(0). Reads (ds_read) always from a buffer made
// resident by the previous iteration's vmcnt+BAR.
// R14-R17 (wave-tile, 32x32 shape, 8-phase, 128x128 TLP) all regressed;
// this keeps R13 byte-identical except the buffering depth and barrier count.
// Exact: fp4 e2m1 +-1 (0x2/0xA), scale E8M0 0x7F=1.0, f32 accum, sums <= 2048.

#define Mdim 16384
#define Ndim 2048
#define Kdim 2048
#define NT 16  // K-tiles of 128 fp4 (64 B rows)

using i32x4 = __attribute__((ext_vector_type(4))) int;
using i32x8 = __attribute__((ext_vector_type(8))) int;
using f32x4 = __attribute__((ext_vector_type(4))) float;

// Binarize f32 -> packed fp4 (+1=0x2, -1=0xA), 16 f32 -> 8 bytes per thread.
__global__ __launch_bounds__(256) void binarize_fp4(const float* __restrict__ x,
                                                    const float* __restrict__ w,
                                                    uint8_t* __restrict__ out,
                                                    int nx16, int ntot16) {
  int i = blockIdx.x * 256 + threadIdx.x;
  if (i >= ntot16) return;
  const float4* p = (i < nx16) ? ((const float4*)x + (size_t)i * 4)
                               : ((const float4*)w + (size_t)(i - nx16) * 4);
  float4 f0 = p[0], f1 = p[1], f2 = p[2], f3 = p[3];
  float s[16] = {f0.x, f0.y, f0.z, f0.w, f1.x, f1.y, f1.z, f1.w,
                 f2.x, f2.y, f2.z, f2.w, f3.x, f3.y, f3.z, f3.w};
  union { uint8_t b[8]; uint2 v; } u;
#pragma unroll
  for (int j = 0; j < 8; ++j) {
    const unsigned lo = s[2 * j] > 0.0f ? 0x2u : 0xAu;
    const unsigned hi = s[2 * j + 1] > 0.0f ? 0x2u : 0xAu;
    u.b[j] = (uint8_t)(lo | (hi << 4));
  }
  ((uint2*)out)[i] = u.v;  // xb4 then wb4, contiguous
}

__device__ __forceinline__ void gl_lds16(const void* gsrc, void* ldst) {
  __builtin_amdgcn_global_load_lds(
      (const __attribute__((address_space(1))) void*)gsrc,
      (__attribute__((address_space(3))) void*)ldst, 16, 0, 0);
}

// fp4 f8f6f4 reads only regs [0:3] of the 8-reg operand: high half undef.
__device__ __forceinline__ i32x8 ext8(i32x4 v) {
  return __builtin_shufflevector(v, v, 0, 1, 2, 3, -1, -1, -1, -1);
}

__global__ __launch_bounds__(512, 1) void bin_gemm_fp4_tb(const uint8_t* __restrict__ A4,
                                                          const uint8_t* __restrict__ W4,
                                                          const float* __restrict__ bias,
                                                          float* __restrict__ C) {
  // Row = 64 B = 128 fp4 of one K-tile. Triple buffer: 3 x (8 KB A + 16 KB B).
  __shared__ __align__(16) uint8_t As[3][128 * 64];
  __shared__ __align__(16) uint8_t Bs[3][256 * 64];

  const int tid = threadIdx.x;
  const int lane = tid & 63;
  const int wid = tid >> 6;  // 0..7
  const int wm = wid >> 2;   // 0..1 (M half: 64 rows)
  const int wn = wid & 3;    // 0..3 (N quarter: 64 cols)

  // XCD swizzle: 1024 blocks, %8==0 -> bijective; the 8 A-panel sharers are
  // co-XCD (L2 reuse of xb4).
  const int bid = blockIdx.x;
  const int swz = (bid & 7) * 128 + (bid >> 3);
  const long brow = (long)(swz >> 3) * 128;  // 128 M-panels
  const long bcol = (long)(swz & 7) * 256;   // 8 col-tiles

  const long rowBytes = Kdim / 2;  // 1024 B per logical row

  // ---- staging: linear LDS dest; swizzle on global SOURCE slot (R13) ----
  const int slin = lane & 3;
  const int sgcol = (slin ^ ((lane >> 3) & 3)) * 16;
  const int srA = wid * 16 + (lane >> 2);  // A rows, 1 gl_lds/wave = 16 rows
  const int srB = wid * 32 + (lane >> 2);  // B rows, 2 gl_lds/wave

  // ---- fragment ds_read offsets (swizzled: slot ^ ((row>>1)&3)) ----
  int offA[4], offB[4];
#pragma unroll
  for (int fr = 0; fr < 4; ++fr) {
    const int ra = wm * 64 + fr * 16 + (lane & 15);
    const int s = lane >> 4;
    offA[fr] = ra * 64 + ((s ^ ((ra >> 1) & 3)) * 16);
  }
#pragma unroll
  for (int fc = 0; fc < 4; ++fc) {
    const int rb = wn * 64 + fc * 16 + (lane & 15);
    const int s = lane >> 4;
    offB[fc] = rb * 64 + ((s ^ ((rb >> 1) & 3)) * 16);
  }

  f32x4 acc[4][4] = {};  // 64 regs
  i32x4 a[4], b[4];

#define BAR() asm volatile("s_barrier" ::: "memory")
#define STAGE(BUF, KT)                                                                  \
  do {                                                                                  \
    const uint8_t* sa_ = A4 + (brow + srA) * rowBytes + ((long)(KT) << 6) + sgcol;      \
    gl_lds16(sa_, &As[BUF][wid * 1024]);                                                \
    const uint8_t* sb_ = W4 + (bcol + srB) * rowBytes + ((long)(KT) << 6) + sgcol;      \
    gl_lds16(sb_, &Bs[BUF][wid * 2048]);                                                \
    gl_lds16(sb_ + 16 * rowBytes, &Bs[BUF][wid * 2048 + 1024]);                         \
  } while (0)

  // ---- prologue: stage tiles 0,1; tile0 resident after vmcnt(3)+BAR.
  STAGE(0, 0);
  STAGE(1, 1);
  asm volatile("s_waitcnt vmcnt(3)" ::: "memory");
  BAR();

  int cur = 0;
#pragma unroll 1
  for (int t = 0; t < NT; ++t) {
    // Stage tile t+2 into buf (cur+2)%3 at the TOP: that buffer's last reads
    // were iter t-1 (lgkm-drained pre-MFMA there) and the end-of-t-1 barrier
    // separates them from this write. Different buffer than cur -> no
    // conflict with this iter's reads.
    if (t + 2 < NT) {
      int stg = cur + 2;
      if (stg >= 3) stg -= 3;
      STAGE(stg, t + 2);
    }

    // reads of buf cur (8 x ds_read_b128); resident per prev iter's vmcnt+BAR
#pragma unroll
    for (int fr = 0; fr < 4; ++fr) a[fr] = *(const i32x4*)&As[cur][offA[fr]];
#pragma unroll
    for (int fc = 0; fc < 4; ++fc) b[fc] = *(const i32x4*)&Bs[cur][offB[fc]];
    asm volatile("s_waitcnt lgkmcnt(0)" ::: "memory");
    __builtin_amdgcn_sched_barrier(0);

    __builtin_amdgcn_s_setprio(1);
#pragma unroll
    for (int fr = 0; fr < 4; ++fr) {
      const i32x8 a8 = ext8(a[fr]);
#pragma unroll
      for (int fc = 0; fc < 4; ++fc) {
        // cbsz=4 (A=fp4), blgp=4 (B=fp4); scales E8M0 0x7F = 1.0 (exact).
        acc[fr][fc] = __builtin_amdgcn_mfma_scale_f32_16x16x128_f8f6f4(
            a8, ext8(b[fc]), acc[fr][fc], 4, 4, 0, 0x7F7F7F7F, 0, 0x7F7F7F7F);
      }
    }
    __builtin_amdgcn_s_setprio(0);

    // Retire tile t+1's stages (3 newest outstanding = tile t+2's, from top).
    if (t < NT - 2) {
      asm volatile("s_waitcnt vmcnt(3)" ::: "memory");
    } else {
      asm volatile("s_waitcnt vmcnt(0)" ::: "memory");
    }
    BAR();  // publish all waves' t+1 stages; also fences next iter's stage

    cur = (cur == 2) ? 0 : cur + 1;
  }

  // ---- epilogue: C/D layout col=lane&15, row=(lane>>4)*4+reg ----
#pragma unroll
  for (int fc = 0; fc < 4; ++fc) {
    const long col = bcol + wn * 64 + fc * 16 + (lane & 15);
    const float bj = bias[col];
#pragma unroll
    for (int fr = 0; fr < 4; ++fr) {
      const long row0 = brow + wm * 64 + fr * 16 + (lane >> 4) * 4;
#pragma unroll
      for (int r = 0; r < 4; ++r) {
        C[(row0 + r) * (long)Ndim + col] = acc[fr][fc][r] + bj;
      }
    }
  }
#undef BAR
#undef STAGE
}

extern "C" void kernel_launch(void* const* d_in, const int* in_sizes, int n_in,
                              void* d_out, int out_size, void* d_ws, size_t ws_size,
                              hipStream_t stream) {
  const float* x = (const float*)d_in[0];
  const float* w = (const float*)d_in[1];
  const float* bias = (const float*)d_in[2];
  float* out = (float*)d_out;

  uint8_t* xb4 = (uint8_t*)d_ws;                 // 16.8 MB (fp4-packed)
  uint8_t* wb4 = xb4 + (size_t)Mdim * Kdim / 2;  // + 2.1 MB (ws >= 18.9 MB)

  const int nx16 = Mdim * Kdim / 16;  // 16-f32 units
  const int nw16 = Ndim * Kdim / 16;
  const int ntot16 = nx16 + nw16;
  binarize_fp4<<<(ntot16 + 255) / 256, 256, 0, stream>>>(x, w, xb4, nx16, ntot16);

  dim3 grid((Mdim / 128) * (Ndim / 256));  // 1024 blocks, %8==0
  bin_gemm_fp4_tb<<<grid, 512, 0, stream>>>(xb4, wb4, bias, out);
}

// Round 19
// 82.440 us; speedup vs baseline: 1.0959x; 1.0355x over previous
//
#include <hip/hip_runtime.h>
#include <stdint.h>

// BinarizeLinear: out[i][j] = sum_k sign(x[i][k]) * sign(W[j][k]) + bias[j]
// R19 = R13 (champion 82.6 µs) with ONE change: the MFMA cluster moves BEFORE
// the first barrier, directly after the ds_reads. R13's order forced a full
// lgkm(0) drain of all 8 reads before BAR1 with MFMA strictly after -> reads
// and MFMA never overlapped (m233's 2-phase stall; slot = 3975 cyc vs ~2100
// of overlapped pipe content). New order lets the compiler emit fine-grained
// lgkmcnt(N) interleaving MFMAs with outstanding reads (m97 behavior), hiding
// read latency under compute. Race ledger IDENTICAL to R13: stage(cur,t+2)
// still issues only after the barrier that follows all reads of cur (the
// lgkm(0) before BAR1 is satisfied for free via MFMA operand deps); vmcnt(3)
// + BAR2 still makes tile t+1 resident + published before its reads; tail
// vmcnt(0). MFMA is register-only so its position vs barriers cannot race.
// Everything else byte-identical R13: 128x256 tile, 8 waves 64x64, BK=128 fp4
// (64 B rows), swizzle slot^((row>>1)&3) on stage-source + ds_read, 1024
// blocks (%8==0 XCD-bijective), 48 KB LDS dbuf, ext8 undef-high operands.
// Exact: fp4 e2m1 +-1 (0x2/0xA), scale E8M0 0x7F=1.0, f32 accum, sums <= 2048.

#define Mdim 16384
#define Ndim 2048
#define Kdim 2048
#define NT 16  // K-tiles of 128 fp4 (64 B rows)

using i32x4 = __attribute__((ext_vector_type(4))) int;
using i32x8 = __attribute__((ext_vector_type(8))) int;
using f32x4 = __attribute__((ext_vector_type(4))) float;

// Binarize f32 -> packed fp4 (+1=0x2, -1=0xA), 16 f32 -> 8 bytes per thread.
__global__ __launch_bounds__(256) void binarize_fp4(const float* __restrict__ x,
                                                    const float* __restrict__ w,
                                                    uint8_t* __restrict__ out,
                                                    int nx16, int ntot16) {
  int i = blockIdx.x * 256 + threadIdx.x;
  if (i >= ntot16) return;
  const float4* p = (i < nx16) ? ((const float4*)x + (size_t)i * 4)
                               : ((const float4*)w + (size_t)(i - nx16) * 4);
  float4 f0 = p[0], f1 = p[1], f2 = p[2], f3 = p[3];
  float s[16] = {f0.x, f0.y, f0.z, f0.w, f1.x, f1.y, f1.z, f1.w,
                 f2.x, f2.y, f2.z, f2.w, f3.x, f3.y, f3.z, f3.w};
  union { uint8_t b[8]; uint2 v; } u;
#pragma unroll
  for (int j = 0; j < 8; ++j) {
    const unsigned lo = s[2 * j] > 0.0f ? 0x2u : 0xAu;
    const unsigned hi = s[2 * j + 1] > 0.0f ? 0x2u : 0xAu;
    u.b[j] = (uint8_t)(lo | (hi << 4));
  }
  ((uint2*)out)[i] = u.v;  // xb4 then wb4, contiguous
}

__device__ __forceinline__ void gl_lds16(const void* gsrc, void* ldst) {
  __builtin_amdgcn_global_load_lds(
      (const __attribute__((address_space(1))) void*)gsrc,
      (__attribute__((address_space(3))) void*)ldst, 16, 0, 0);
}

// fp4 f8f6f4 reads only regs [0:3] of the 8-reg operand: high half undef.
__device__ __forceinline__ i32x8 ext8(i32x4 v) {
  return __builtin_shufflevector(v, v, 0, 1, 2, 3, -1, -1, -1, -1);
}

__global__ __launch_bounds__(512, 1) void bin_gemm_fp4_ov(const uint8_t* __restrict__ A4,
                                                          const uint8_t* __restrict__ W4,
                                                          const float* __restrict__ bias,
                                                          float* __restrict__ C) {
  // Row = 64 B = 128 fp4 of one K-tile. A: [2][128 rows], B: [2][256 rows]. 48 KB.
  __shared__ __align__(16) uint8_t As[2][128 * 64];
  __shared__ __align__(16) uint8_t Bs[2][256 * 64];

  const int tid = threadIdx.x;
  const int lane = tid & 63;
  const int wid = tid >> 6;  // 0..7
  const int wm = wid >> 2;   // 0..1 (M half: 64 rows)
  const int wn = wid & 3;    // 0..3 (N quarter: 64 cols)

  // XCD swizzle: 1024 blocks, %8==0 -> bijective; the 8 A-panel sharers are
  // co-XCD (L2 reuse of xb4).
  const int bid = blockIdx.x;
  const int swz = (bid & 7) * 128 + (bid >> 3);
  const long brow = (long)(swz >> 3) * 128;  // 128 M-panels
  const long bcol = (long)(swz & 7) * 256;   // 8 col-tiles

  const long rowBytes = Kdim / 2;  // 1024 B per logical row

  // ---- staging: linear LDS dest; swizzle on global SOURCE slot (R13) ----
  const int slin = lane & 3;
  const int sgcol = (slin ^ ((lane >> 3) & 3)) * 16;
  const int srA = wid * 16 + (lane >> 2);  // A rows, 1 gl_lds/wave = 16 rows
  const int srB = wid * 32 + (lane >> 2);  // B rows, 2 gl_lds/wave

  // ---- fragment ds_read offsets (swizzled: slot ^ ((row>>1)&3)) ----
  int offA[4], offB[4];
#pragma unroll
  for (int fr = 0; fr < 4; ++fr) {
    const int ra = wm * 64 + fr * 16 + (lane & 15);
    const int s = lane >> 4;
    offA[fr] = ra * 64 + ((s ^ ((ra >> 1) & 3)) * 16);
  }
#pragma unroll
  for (int fc = 0; fc < 4; ++fc) {
    const int rb = wn * 64 + fc * 16 + (lane & 15);
    const int s = lane >> 4;
    offB[fc] = rb * 64 + ((s ^ ((rb >> 1) & 3)) * 16);
  }

  f32x4 acc[4][4] = {};  // 64 regs
  i32x4 a[4], b[4];

#define BAR() asm volatile("s_barrier" ::: "memory")
#define STAGE(BUF, KT)                                                                  \
  do {                                                                                  \
    const uint8_t* sa_ = A4 + (brow + srA) * rowBytes + ((long)(KT) << 6) + sgcol;      \
    gl_lds16(sa_, &As[BUF][wid * 1024]);                                                \
    const uint8_t* sb_ = W4 + (bcol + srB) * rowBytes + ((long)(KT) << 6) + sgcol;      \
    gl_lds16(sb_, &Bs[BUF][wid * 2048]);                                                \
    gl_lds16(sb_ + 16 * rowBytes, &Bs[BUF][wid * 2048 + 1024]);                         \
  } while (0)

  // ---- prologue: stage tiles 0,1 (3 gl_lds/wave each); tile0 resident.
  STAGE(0, 0);
  STAGE(1, 1);
  asm volatile("s_waitcnt vmcnt(3)" ::: "memory");
  BAR();

#pragma unroll 1
  for (int t = 0; t < NT; ++t) {
    const int cur = t & 1;

    // reads of buf cur (8 x ds_read_b128) -- resident per prev iter's
    // vmcnt+BAR.  NO forced drain here: the compiler interleaves the MFMA
    // cluster below with fine-grained lgkmcnt(N) waits, hiding read latency.
#pragma unroll
    for (int fr = 0; fr < 4; ++fr) a[fr] = *(const i32x4*)&As[cur][offA[fr]];
#pragma unroll
    for (int fc = 0; fc < 4; ++fc) b[fc] = *(const i32x4*)&Bs[cur][offB[fc]];

    __builtin_amdgcn_s_setprio(1);
#pragma unroll
    for (int fr = 0; fr < 4; ++fr) {
      const i32x8 a8 = ext8(a[fr]);
#pragma unroll
      for (int fc = 0; fc < 4; ++fc) {
        // cbsz=4 (A=fp4), blgp=4 (B=fp4); scales E8M0 0x7F = 1.0 (exact).
        acc[fr][fc] = __builtin_amdgcn_mfma_scale_f32_16x16x128_f8f6f4(
            a8, ext8(b[fc]), acc[fr][fc], 4, 4, 0, 0x7F7F7F7F, 0, 0x7F7F7F7F);
      }
    }
    __builtin_amdgcn_s_setprio(0);

    // All reads of cur are complete (MFMA operand deps); lgkm(0) is free and
    // guarantees it explicitly before the barrier.
    asm volatile("s_waitcnt lgkmcnt(0)" ::: "memory");
    BAR();  // block-wide: everyone done reading buf cur

    // overwrite cur with tile t+2 (post-barrier: safe; ledger = R13)
    if (t + 2 < NT) STAGE(cur, t + 2);

    // retire tile t+1's stages (3 newest outstanding = tile t+2's, just issued)
    if (t < NT - 2) {
      asm volatile("s_waitcnt vmcnt(3)" ::: "memory");
    } else {
      asm volatile("s_waitcnt vmcnt(0)" ::: "memory");
    }
    BAR();  // tile t+1 resident + published for next iter's reads
  }

  // ---- epilogue: C/D layout col=lane&15, row=(lane>>4)*4+reg ----
#pragma unroll
  for (int fc = 0; fc < 4; ++fc) {
    const long col = bcol + wn * 64 + fc * 16 + (lane & 15);
    const float bj = bias[col];
#pragma unroll
    for (int fr = 0; fr < 4; ++fr) {
      const long row0 = brow + wm * 64 + fr * 16 + (lane >> 4) * 4;
#pragma unroll
      for (int r = 0; r < 4; ++r) {
        C[(row0 + r) * (long)Ndim + col] = acc[fr][fc][r] + bj;
      }
    }
  }
#undef BAR
#undef STAGE
}

extern "C" void kernel_launch(void* const* d_in, const int* in_sizes, int n_in,
                              void* d_out, int out_size, void* d_ws, size_t ws_size,
                              hipStream_t stream) {
  const float* x = (const float*)d_in[0];
  const float* w = (const float*)d_in[1];
  const float* bias = (const float*)d_in[2];
  float* out = (float*)d_out;

  uint8_t* xb4 = (uint8_t*)d_ws;                 // 16.8 MB (fp4-packed)
  uint8_t* wb4 = xb4 + (size_t)Mdim * Kdim / 2;  // + 2.1 MB (ws >= 18.9 MB)

  const int nx16 = Mdim * Kdim / 16;  // 16-f32 units
  const int nw16 = Ndim * Kdim / 16;
  const int ntot16 = nx16 + nw16;
  binarize_fp4<<<(ntot16 + 255) / 256, 256, 0, stream>>>(x, w, xb4, nx16, ntot16);

  dim3 grid((Mdim / 128) * (Ndim / 256));  // 1024 blocks, %8==0
  bin_gemm_fp4_ov<<<grid, 512, 0, stream>>>(xb4, wb4, bias, out);
}